// Round 18
// baseline (121.724 us; speedup 1.0000x reference)
//
#include <hip/hip_runtime.h>

#define IMG_H 512
#define IMG_W 512
#define IMGSZ (IMG_H * IMG_W)
#define NIMG 48                       // B*C
#define NB 16
#define NPOS 4096
#define DNPIX 12582912.0              // 48*512*512

// Band-streaming SSIM config (r4 structure: LDS vrow, 2 cols/thread)
#define BH 16                         // output rows per block band
#define NBANDS (IMG_H / BH)           // 32
#define SSIM_BLOCKS (NIMG * NBANDS)   // 1536 (divisible by 8)
#define TOTAL_BLOCKS SSIM_BLOCKS
#define WPB 4                         // 256 threads = 4 waves
#define VROW_P 544                    // physical row length after pad-32 swizzle

// pad-every-32 swizzle: stride-2 column access becomes 2-way (free) not 4-way
__device__ __forceinline__ int phys(int i) { return i + (i >> 5); }

__global__ __launch_bounds__(256) void fused_kernel(
    const float* __restrict__ pred, const float* __restrict__ targ,
    const int* __restrict__ pos32, const float* __restrict__ imp,
    double* __restrict__ acc, unsigned int* __restrict__ cnt,
    float* __restrict__ out)
{
    __shared__ float vrow[4][VROW_P];
    __shared__ float red[3][WPB];

    const int tid = threadIdx.x;
    const int lane = tid & 63;
    const int wid = tid >> 6;
    const int bid = blockIdx.x;

    // bijective XCD swizzle: same-XCD blocks cover contiguous bands
    int s = (bid & 7) * (SSIM_BLOCKS / 8) + (bid >> 3);
    const int img = s >> 5;            // NBANDS == 32
    const int band = s & 31;
    const int row0 = band * BH;
    const float* __restrict__ pimg = pred + (size_t)img * IMGSZ;
    const float* __restrict__ timg = targ + (size_t)img * IMGSZ;
    const int c0 = 2 * tid;            // this thread owns columns c0, c0+1

    // zero LDS once (edge/pad columns stay zero forever)
    float* vflat = &vrow[0][0];
    for (int i = tid; i < 4 * VROW_P; i += 256) vflat[i] = 0.f;
    __syncthreads();

    // vertical running sums (11 rows) for col c0 (v*) and c0+1 (w*):
    // x, y, x^2+y^2 (merged), xy
    float vx = 0.f, vy = 0.f, v2 = 0.f, vxy = 0.f;
    float wx = 0.f, wy = 0.f, w2 = 0.f, wxy = 0.f;
    float perc = 0.f, ssim_s = 0.f, samp = 0.f;

    // ---- warm-up: rows row0-5 .. row0+5 ----
    for (int k = 0; k < 11; ++k) {
        int gr = row0 - 5 + k;
        float2 xv = make_float2(0.f, 0.f), yv = make_float2(0.f, 0.f);
        if (gr >= 0 && gr < IMG_H) {
            xv = *(const float2*)(pimg + gr * IMG_W + c0);
            yv = *(const float2*)(timg + gr * IMG_W + c0);
            if (gr >= row0)   // in-band part of warm-up (gr <= row0+5 < row0+BH)
                perc += fabsf(xv.x - yv.x) + fabsf(xv.y - yv.y);
        }
        vx += xv.x; vy += yv.x;
        v2 = fmaf(xv.x, xv.x, fmaf(yv.x, yv.x, v2));
        vxy = fmaf(xv.x, yv.x, vxy);
        wx += xv.y; wy += yv.y;
        w2 = fmaf(xv.y, xv.y, fmaf(yv.y, yv.y, w2));
        wxy = fmaf(xv.y, yv.y, wxy);
    }

    const float inv121 = 1.0f / 121.0f;
    const float inv121x2 = 2.0f / 121.0f;
    const float C1c = 1e-4f, CC = 1e-4f + 9e-4f;   // C1, C1+C2

    // ---- stream down the band ----
    for (int r = 0; r < BH; ++r) {
        if (r > 0) {
            int ge = row0 + r + 5;   // entering row (>= row0+6 > 0)
            int gl = row0 + r - 6;   // leaving row  (<= row0+BH-7 < IMG_H)
            float2 xe = make_float2(0.f, 0.f), ye = make_float2(0.f, 0.f);
            float2 xl = make_float2(0.f, 0.f), yl = make_float2(0.f, 0.f);
            if (ge < IMG_H) {
                xe = *(const float2*)(pimg + ge * IMG_W + c0);
                ye = *(const float2*)(timg + ge * IMG_W + c0);
                if (ge < row0 + BH)   // entering row inside this band
                    perc += fabsf(xe.x - ye.x) + fabsf(xe.y - ye.y);
            }
            if (gl >= 0) {
                xl = *(const float2*)(pimg + gl * IMG_W + c0);
                yl = *(const float2*)(timg + gl * IMG_W + c0);
            }
            vx += xe.x - xl.x;
            vy += ye.x - yl.x;
            v2 += fmaf(xe.x, xe.x, fmaf(ye.x, ye.x,
                  -fmaf(xl.x, xl.x, yl.x * yl.x)));
            vxy = fmaf(-xl.x, yl.x, fmaf(xe.x, ye.x, vxy));
            wx += xe.y - xl.y;
            wy += ye.y - yl.y;
            w2 += fmaf(xe.y, xe.y, fmaf(ye.y, ye.y,
                  -fmaf(xl.y, xl.y, yl.y * yl.y)));
            wxy = fmaf(-xl.y, yl.y, fmaf(xe.y, ye.y, wxy));
        }

        // publish vertical sums for this output row
        int p0 = phys(6 + c0), p1 = phys(6 + c0 + 1);
        vrow[0][p0] = vx;  vrow[0][p1] = wx;
        vrow[1][p0] = vy;  vrow[1][p1] = wy;
        vrow[2][p0] = v2;  vrow[2][p1] = w2;
        vrow[3][p0] = vxy; vrow[3][p1] = wxy;
        __syncthreads();

        // horizontal 11-tap for col c0, then slide to c0+1
        float Sx = 0.f, Sy = 0.f, S2 = 0.f, Sxy = 0.f;
        int base = 6 + c0 - 5;
#pragma unroll
        for (int dx = 0; dx < 11; ++dx) {
            int pi = phys(base + dx);
            Sx  += vrow[0][pi];
            Sy  += vrow[1][pi];
            S2  += vrow[2][pi];
            Sxy += vrow[3][pi];
        }
        {
            float mux = Sx * inv121, muy = Sy * inv121;
            float den1 = fmaf(mux, mux, fmaf(muy, muy, C1c));
            float num1 = fmaf(mux + mux, muy, C1c);
            float den2 = fmaf(S2, inv121, CC - den1);
            float num2 = fmaf(Sxy, inv121x2, CC - num1);
            ssim_s += __fdividef(num1 * num2, den1 * den2);
        }
        int pa = phys(6 + c0 + 6), ps = phys(6 + c0 - 5);
        Sx  += vrow[0][pa] - vrow[0][ps];
        Sy  += vrow[1][pa] - vrow[1][ps];
        S2  += vrow[2][pa] - vrow[2][ps];
        Sxy += vrow[3][pa] - vrow[3][ps];
        {
            float mux = Sx * inv121, muy = Sy * inv121;
            float den1 = fmaf(mux, mux, fmaf(muy, muy, C1c));
            float num1 = fmaf(mux + mux, muy, C1c);
            float den2 = fmaf(S2, inv121, CC - den1);
            float num2 = fmaf(Sxy, inv121x2, CC - num1);
            ssim_s += __fdividef(num1 * num2, den1 * den2);
        }
        __syncthreads();   // WAR: next row overwrites vrow
    }

    // ---------------- sampled loss, spread over all blocks/waves ----------
    // block bid owns samples [bid*NPOS/1536, (bid+1)*NPOS/1536) — 2 or 3;
    // wave w handles one; 64 lanes cooperate (48 pixels + 16 weights).
    {
        int n0 = (bid * NPOS) / SSIM_BLOCKS;
        int n1 = ((bid + 1) * NPOS) / SSIM_BLOCKS;
        // layout probe once: first 64 odd 32-bit words all zero <=> int64
        unsigned long long ball = __ballot(pos32[2 * lane + 1] != 0);
        for (int n = n0 + wid; n < n1; n += WPB) {
            int u, v;
            if (ball == 0ull) { u = pos32[4 * n]; v = pos32[4 * n + 2]; }
            else              { u = pos32[2 * n]; v = pos32[2 * n + 1]; }
            int off = u * IMG_W + v;
            float a = 0.f, w = 0.f;
            if (lane < NIMG) {
                float d = pred[(size_t)lane * IMGSZ + off]
                        - targ[(size_t)lane * IMGSZ + off];
                a = d * d;
            } else {
                w = 1.0f / (imp[(size_t)(lane - NIMG) * IMGSZ + off] + 0.1f);
            }
#pragma unroll
            for (int o = 32; o > 0; o >>= 1) {
                a += __shfl_down(a, o);
                w += __shfl_down(w, o);
            }
            if (lane == 0)
                samp += (w * (1.0f / 16.0f)) * (a * (1.0f / 48.0f));
        }
    }

    // ---------------- reduction: wave -> block -> atomics ----------------
#pragma unroll
    for (int o = 32; o > 0; o >>= 1) {
        ssim_s += __shfl_down(ssim_s, o);
        perc   += __shfl_down(perc, o);
    }
    if (lane == 0) { red[0][wid] = ssim_s; red[1][wid] = perc; red[2][wid] = samp; }
    __syncthreads();
    if (tid == 0) {
        float ss = 0.f, pp = 0.f, mm = 0.f;
#pragma unroll
        for (int k = 0; k < WPB; ++k) {
            ss += red[0][k]; pp += red[1][k]; mm += red[2][k];
        }
        atomicAdd(&acc[0], (double)ss);
        atomicAdd(&acc[1], (double)pp);
        atomicAdd(&acc[2], (double)mm);
        __threadfence();
        unsigned int old = atomicAdd(cnt, 1u);
        if (old == TOTAL_BLOCKS - 1) {
            double s0 = atomicAdd(&acc[0], 0.0);
            double s1 = atomicAdd(&acc[1], 0.0);
            double s2 = atomicAdd(&acc[2], 0.0);
            double sampled = s2 / (double)NPOS;
            double perceptual = s1 / DNPIX;
            double structural = 1.0 - s0 / DNPIX;
            double total = 0.3 * sampled + 0.4 * perceptual + 0.2 * structural;
            out[0] = (float)total;
            out[1] = (float)sampled;
            out[2] = (float)perceptual;
            out[3] = (float)structural;
            out[4] = 0.0f;
        }
    }
}

extern "C" void kernel_launch(void* const* d_in, const int* in_sizes, int n_in,
                              void* d_out, int out_size, void* d_ws, size_t ws_size,
                              hipStream_t stream)
{
    const float* pred = (const float*)d_in[0];
    const float* targ = (const float*)d_in[1];
    const int* pos = (const int*)d_in[2];
    const float* imp = (const float*)d_in[3];
    float* out = (float*)d_out;
    double* acc = (double*)d_ws;                       // acc[0..2]
    unsigned int* cnt = (unsigned int*)((char*)d_ws + 24);

    hipMemsetAsync(d_ws, 0, 32, stream);
    hipLaunchKernelGGL(fused_kernel, dim3(TOTAL_BLOCKS), dim3(256), 0, stream,
                       pred, targ, pos, imp, acc, cnt, out);
}